// Round 1
// baseline (146.734 us; speedup 1.0000x reference)
//
#include <hip/hip_runtime.h>

// VQC 12-qubit statevector, batch=1024. 256 threads/block (4 waves), one batch
// element per block, NR=16 float2 regs/thread.
// Occupancy: 4 blocks/CU (LDS 32.96 KB) x 4 waves = 16 waves/CU = 4 waves/SIMD
// (2x the previous 128-thread kernel, which was total-parallelism-limited).
//
// Flat index i (12 bits), qubit q <-> bit (11-q).
// Layout A: b11b10=w (q0,q1), b9..b6=reg (q2..q5), b5..b0=lane (q6..q11)
// Layout B: b11b10=w (q0,q1), b9..b4=lane (q2..q7), b3..b0=reg (q8..q11)
//
// Per layer: Y q2..q5 in-reg [A]; A->B exchange (fuses Y_q6,Y_q7; WAVE-LOCAL:
// each wave owns an 8KB region, sync = lgkmcnt(0) only, no block barrier);
// Y q8..q11 in-reg [B]; fused Z (all 12 qubits, Gray-code running product);
// B->A exchange (fuses CNOT-chain permutation x = y^(y>>1) AND the NEXT
// layer's Y_q0,Y_q1 across the 4 waves; 2 block barriers). Layer-0 Y_q0,Y_q1
// folded into the closed-form encoding; last layer's Zs are no-ops for |amp|^2.
//
// LDS: single 32KB buffer, XOR-swizzled (byte ^= ((byte>>9)&7)<<4). Per-pattern
// bank analysis: AB writes 4/bank (b64 floor), AB reads 2/bank (floor, 4-lane
// broadcast), BA reads 8/bank (b128 floor), BA writes 8/bank (2x b64 floor,
// 16 ops/layer -> negligible). Gather inputs are contiguous 32B -> 2x b128.

#define PI_F 3.14159265358979323846f
#define NR 16

__device__ __forceinline__ float2 cmul(float2 a, float2 b) {
    return make_float2(a.x*b.x - a.y*b.y, a.x*b.y + a.y*b.x);
}
__device__ __forceinline__ float2 cmulc(float2 a, float2 b) {  // a * conj(b)
    return make_float2(a.x*b.x + a.y*b.y, a.y*b.x - a.x*b.y);
}

template<int RB>
__device__ __forceinline__ void ypow_reg(float2 (&a)[NR], float c, float s) {
    #pragma unroll
    for (int r0 = 0; r0 < NR; ++r0) {
        if ((r0 >> RB) & 1) continue;
        const int r1 = r0 | (1 << RB);
        float2 a0 = a[r0], a1 = a[r1];
        a[r0] = make_float2(c*a0.x - s*a1.x, c*a0.y - s*a1.y);
        a[r1] = make_float2(s*a0.x + c*a1.x, s*a0.y + c*a1.y);
    }
}

__device__ __forceinline__ void ypowA(float2 (&a)[NR], const float* __restrict__ th) {
    // layout A reg bit 3..0 = b9..b6 = q2..q5
    { float s,c; __sincosf(0.5f*PI_F*th[4],  &s,&c); ypow_reg<3>(a,c,s); }   // q2
    { float s,c; __sincosf(0.5f*PI_F*th[6],  &s,&c); ypow_reg<2>(a,c,s); }   // q3
    { float s,c; __sincosf(0.5f*PI_F*th[8],  &s,&c); ypow_reg<1>(a,c,s); }   // q4
    { float s,c; __sincosf(0.5f*PI_F*th[10], &s,&c); ypow_reg<0>(a,c,s); }   // q5
}
__device__ __forceinline__ void ypowB(float2 (&a)[NR], const float* __restrict__ th) {
    // layout B reg bit 3..0 = b3..b0 = q8..q11
    { float s,c; __sincosf(0.5f*PI_F*th[16], &s,&c); ypow_reg<3>(a,c,s); }   // q8
    { float s,c; __sincosf(0.5f*PI_F*th[18], &s,&c); ypow_reg<2>(a,c,s); }   // q9
    { float s,c; __sincosf(0.5f*PI_F*th[20], &s,&c); ypow_reg<1>(a,c,s); }   // q10
    { float s,c; __sincosf(0.5f*PI_F*th[22], &s,&c); ypow_reg<0>(a,c,s); }   // q11
}

// A->B transpose fusing Y_q6 (b5) and Y_q7 (b4). Wave-local (b11b10 untouched):
// wave w uses region [w*8192, w*8192+8192). Region slot = (x[9:6]<<4 | x[3:0])*4
// + x[5:4], so the 4 (b5,b4) gather inputs are a contiguous 32B run.
template<bool PRE_SYNC>
__device__ __forceinline__ void exchange_AB(float2 (&a)[NR], char* bufc,
                                            int w, int lane,
                                            float c6, float s6, float c7, float s7) {
    if (PRE_SYNC) __syncthreads();   // other waves' BA reads still cover this region
    const int wbyte = (w << 13) | ((lane & 15) << 5) | ((lane >> 4) << 3);
    #pragma unroll
    for (int r = 0; r < NR; ++r)     // amp x = w<<10 | r<<6 | lane
        *(float2*)(bufc + ((wbyte | (r << 9)) ^ ((r & 7) << 4))) = a[r];
    // wave-local write->read ordering: lockstep issue + lgkmcnt drain
    asm volatile("s_waitcnt lgkmcnt(0)" ::: "memory");
    const int g = lane >> 2;                        // output y[9:6]
    const float y60 = (lane & 2) ? s6 : c6;         // Y6[b5',0]  (b5' = L1)
    const float y61 = (lane & 2) ? c6 : -s6;        // Y6[b5',1]
    const float y70 = (lane & 1) ? s7 : c7;         // Y7[b4',0]  (b4' = L0)
    const float y71 = (lane & 1) ? c7 : -s7;        // Y7[b4',1]
    const float k00 = y60*y70, k01 = y60*y71, k10 = y61*y70, k11 = y61*y71;
    const int rbyte = (w << 13) | (g << 9);
    const int kx = (g & 7) << 4;                    // swizzle key, const per thread
    #pragma unroll
    for (int R = 0; R < NR; ++R) {                  // out y = w<<10 | L<<4 | R
        const int base = rbyte | (R << 5);
        float4 p01 = *(const float4*)(bufc + (base ^ kx));         // (b5b4)=00,01
        float4 p23 = *(const float4*)(bufc + ((base | 16) ^ kx));  // (b5b4)=10,11
        a[R] = make_float2(k00*p01.x + k01*p01.z + k10*p23.x + k11*p23.z,
                           k00*p01.y + k01*p01.w + k10*p23.y + k11*p23.w);
    }
}

// B->A transpose fusing the CNOT-chain permutation (input x = y ^ (y>>1)) and
// the NEXT layer's Y_q0 (b11), Y_q1 (b10). Cross-wave. Store amp x at
// slot = T*4 + u*2 + v with v = x11, u = x10^x11, T = ((x9^u)<<9) | x[8:0];
// then the 4 (b11',b10') gather inputs for output y sit at slots t*4..t*4+3,
// t = y[9:0] ^ (y[9:0]>>1).
__device__ __forceinline__ void exchange_BA(float2 (&a)[NR], char* bufc,
                                            int w, int lane,
                                            float c0, float s0, float c1, float s1) {
    __syncthreads();                 // all waves done with their AB-region reads
    const int v_  = (w >> 1) & 1;
    const int u_  = v_ ^ (w & 1);
    const int l5u = (lane >> 5) ^ u_;
    const int wbyte = (l5u << 14) | ((lane & 31) << 9) | (u_ << 4) | (v_ << 3);
    const int wkx = (lane & 7) << 4;
    #pragma unroll
    for (int R = 0; R < NR; ++R)     // amp x = w<<10 | lane<<4 | R (layout B)
        *(float2*)(bufc + ((wbyte | (R << 5)) ^ wkx)) = a[R];
    __syncthreads();
    const float ky00 = (w & 2) ? s0 : c0;     // Y0[y11,0]
    const float ky01 = (w & 2) ? c0 : -s0;    // Y0[y11,1]
    const float ky10 = (w & 1) ? s1 : c1;     // Y1[y10,0]
    const float ky11 = (w & 1) ? c1 : -s1;    // Y1[y10,1]
    const float k00 = ky10*ky00, k01 = ky10*ky01, k10 = ky11*ky00, k11 = ky11*ky01;
    #pragma unroll
    for (int r = 0; r < NR; ++r) {            // out y = w<<10 | r<<6 | lane (layout A)
        const int ylow = (r << 6) | lane;
        const int t = ylow ^ (ylow >> 1);     // 10-bit Gray inverse
        const int base = t << 5;
        const int kx = t & 0x70;              // ((base>>9)&7)<<4
        float4 p01 = *(const float4*)(bufc + (base ^ kx));         // (u,v)=00,01
        float4 p23 = *(const float4*)(bufc + ((base | 16) ^ kx));  // (u,v)=10,11
        a[r] = make_float2(k00*p01.x + k01*p01.z + k10*p23.x + k11*p23.z,
                           k00*p01.y + k01*p01.w + k10*p23.y + k11*p23.w);
    }
}

// Fused Z for all 12 qubits, state in layout B. Per-amp factor as a Gray-code
// running complex product (1 sincos for the wave+lane part, 4 for reg bits).
__device__ __forceinline__ void fused_z_B(float2 (&a)[NR], int w, int lane,
                                          const float* __restrict__ th) {
    float alpha = ((w & 2) ? th[1] : 0.0f) + ((w & 1) ? th[3] : 0.0f);  // q0,q1
    #pragma unroll
    for (int k = 0; k < 6; ++k)               // lane bit k <-> q(7-k)
        alpha += ((lane >> k) & 1) ? th[2*(7-k)+1] : 0.0f;
    float2 zb; __sincosf(PI_F * alpha, &zb.y, &zb.x);
    float2 zq[4];
    #pragma unroll
    for (int j = 0; j < 4; ++j)               // reg bit j <-> q(11-j)
        __sincosf(PI_F * th[2*(11-j)+1], &zq[j].y, &zq[j].x);
    float2 cur = zb;
    a[0] = cmul(a[0], cur);
    #pragma unroll
    for (int k = 1; k < NR; ++k) {
        const int bit = __builtin_ctz(k);
        const int g = k ^ (k >> 1);
        cur = ((g >> bit) & 1) ? cmul(cur, zq[bit]) : cmulc(cur, zq[bit]);
        a[g] = cmul(a[g], cur);
    }
}

__global__ __launch_bounds__(256, 4) void vqc_kernel(
    const float* __restrict__ inputs,   // [1024,12]
    const float* __restrict__ thetas,   // [72] = [3][12][2]
    float* __restrict__ out)            // [1024,12]
{
    __shared__ __align__(16) char bufc[32768];   // swizzled exchange buffer
    __shared__ float redBuf[48];

    const int b = blockIdx.x;
    const int tid = threadIdx.x;
    const int w = tid >> 6;          // w1=b11(q0), w0=b10(q1)
    const int lane = tid & 63;
    const float* x = inputs + b * 12;

    float2 a[NR];

    // ---- Encoding (closed form) with layer-0 Y_q0 AND Y_q1 folded in.
    // amp = 2^-6 * F0(b11) * F1(b10) * cis(pi * sum_{q>=2 set} x_q)
    float phb = 0.0f;
    #pragma unroll
    for (int k = 0; k < 6; ++k)               // layout A lane bit k <-> q(11-k)
        phb += ((lane >> k) & 1) ? x[11 - k] : 0.0f;
    float2 cisb; __sincosf(PI_F * phb, &cisb.y, &cisb.x);
    float2 E0; __sincosf(PI_F * x[0], &E0.y, &E0.x);
    float2 E1; __sincosf(PI_F * x[1], &E1.y, &E1.x);
    float sa, ca; __sincosf(0.5f * PI_F * thetas[0], &sa, &ca);
    float sb, cb; __sincosf(0.5f * PI_F * thetas[2], &sb, &cb);
    float2 F0 = (w & 2) ? make_float2(sa + ca*E0.x,  ca*E0.y)
                        : make_float2(ca - sa*E0.x, -sa*E0.y);
    float2 F1 = (w & 1) ? make_float2(sb + cb*E1.x,  cb*E1.y)
                        : make_float2(cb - sb*E1.x, -sb*E1.y);
    float2 g0 = cmul(cmul(F0, F1), cisb);
    g0.x *= 0.015625f; g0.y *= 0.015625f;
    float2 zr[4];
    #pragma unroll
    for (int j = 0; j < 4; ++j)               // layout A reg bit j <-> q(5-j)
        __sincosf(PI_F * x[5 - j], &zr[j].y, &zr[j].x);
    {
        float2 cur = g0;
        a[0] = cur;
        #pragma unroll
        for (int k = 1; k < NR; ++k) {
            const int bit = __builtin_ctz(k);
            const int g = k ^ (k >> 1);
            cur = ((g >> bit) & 1) ? cmul(cur, zr[bit]) : cmulc(cur, zr[bit]);
            a[g] = cur;
        }
    }

    const float* th0 = thetas;
    const float* th1 = thetas + 24;
    const float* th2 = thetas + 48;

    // ----- layer 0 -----
    ypowA(a, th0);
    { float s6,c6,s7,c7;
      __sincosf(0.5f*PI_F*th0[12], &s6,&c6);
      __sincosf(0.5f*PI_F*th0[14], &s7,&c7);
      exchange_AB<false>(a, bufc, w, lane, c6,s6,c7,s7); }
    ypowB(a, th0);
    fused_z_B(a, w, lane, th0);
    { float s0,c0,s1,c1;
      __sincosf(0.5f*PI_F*th1[0], &s0,&c0);
      __sincosf(0.5f*PI_F*th1[2], &s1,&c1);
      exchange_BA(a, bufc, w, lane, c0,s0,c1,s1); }

    // ----- layer 1 -----
    ypowA(a, th1);
    { float s6,c6,s7,c7;
      __sincosf(0.5f*PI_F*th1[12], &s6,&c6);
      __sincosf(0.5f*PI_F*th1[14], &s7,&c7);
      exchange_AB<true>(a, bufc, w, lane, c6,s6,c7,s7); }
    ypowB(a, th1);
    fused_z_B(a, w, lane, th1);
    { float s0,c0,s1,c1;
      __sincosf(0.5f*PI_F*th2[0], &s0,&c0);
      __sincosf(0.5f*PI_F*th2[2], &s1,&c1);
      exchange_BA(a, bufc, w, lane, c0,s0,c1,s1); }

    // ----- layer 2 (no CNOT; Zs dropped — diagonal before |amp|^2) -----
    ypowA(a, th2);
    { float s6,c6,s7,c7;
      __sincosf(0.5f*PI_F*th2[12], &s6,&c6);
      __sincosf(0.5f*PI_F*th2[14], &s7,&c7);
      exchange_AB<true>(a, bufc, w, lane, c6,s6,c7,s7); }
    ypowB(a, th2);

    // ---- Readout in layout B: q0=w1, q1=w0, q2..q7=lane bits 5..0, q8..q11=reg
    float totalP = 0.0f;
    float D[4] = {0, 0, 0, 0};
    #pragma unroll
    for (int r = 0; r < NR; ++r) {
        const float p = a[r].x * a[r].x + a[r].y * a[r].y;
        totalP += p;
        #pragma unroll
        for (int j = 0; j < 4; ++j)
            D[j] += ((r >> j) & 1) ? -p : p;
    }
    #pragma unroll
    for (int q = 0; q < 12; ++q) {
        float v;
        if (q == 0)      v = (w & 2) ? -totalP : totalP;
        else if (q == 1) v = (w & 1) ? -totalP : totalP;
        else if (q <= 7) v = ((lane >> (7 - q)) & 1) ? -totalP : totalP;
        else             v = D[11 - q];
        #pragma unroll
        for (int off = 32; off >= 1; off >>= 1)
            v += __shfl_xor(v, off, 64);
        if (lane == 0) redBuf[w * 12 + q] = v;
    }
    __syncthreads();
    if (tid < 12)
        out[b * 12 + tid] = redBuf[tid] + redBuf[12 + tid]
                          + redBuf[24 + tid] + redBuf[36 + tid];
}

extern "C" void kernel_launch(void* const* d_in, const int* in_sizes, int n_in,
                              void* d_out, int out_size, void* d_ws, size_t ws_size,
                              hipStream_t stream) {
    const float* inputs = (const float*)d_in[0];   // [1024,12] f32
    const float* thetas = (const float*)d_in[1];   // [72] f32
    float* out = (float*)d_out;                    // [1024,12] f32
    vqc_kernel<<<dim3(1024), dim3(256), 0, stream>>>(inputs, thetas, out);
}

// Round 2
// 84.669 us; speedup vs baseline: 1.7330x; 1.7330x over previous
//
#include <hip/hip_runtime.h>

// VQC 12-qubit statevector, batch=1024. 256 threads/block (4 waves), one batch
// element per block, NR=16 float2 regs/thread.
//
// R1 post-mortem: __launch_bounds__(256,4) clamped VGPRs to 64 -> ~550 B/thread
// scratch spill (145 MB WRITE_SIZE, 97 us). Fix: no min-waves clamp; instead
// bound register pressure structurally (gather loops chunked by 4 with
// compile-time memory fences -> <=8 float4 loads in flight). Target: natural
// VGPR <= 128 -> 4 blocks/CU -> 16 waves/CU with zero spill.
//
// Flat index i (12 bits), qubit q <-> bit (11-q).
// Layout A: b11b10=w (q0,q1), b9..b6=reg (q2..q5), b5..b0=lane (q6..q11)
// Layout B: b11b10=w (q0,q1), b9..b4=lane (q2..q7), b3..b0=reg (q8..q11)
//
// Per layer: Y q2..q5 in-reg [A]; A->B exchange (fuses Y_q6,Y_q7; WAVE-LOCAL:
// each wave owns an 8KB region, sync = lgkmcnt(0) only, no block barrier);
// Y q8..q11 in-reg [B]; fused Z (all 12 qubits, Gray-code running product);
// B->A exchange (fuses CNOT-chain permutation x = y^(y>>1) AND the NEXT
// layer's Y_q0,Y_q1 across the 4 waves; 2 block barriers). Layer-0 Y_q0,Y_q1
// folded into the closed-form encoding; last layer's Zs are no-ops for |amp|^2.
//
// LDS: single 32KB buffer, XOR-swizzled (byte ^= ((byte>>9)&7)<<4). Bank
// analysis: AB writes uniform 4 touches/bank (b64 floor), AB reads 2x floor
// w/ 4-lane broadcast, BA reads at b128 floor (64 distinct addrs), BA writes
// 2x b64 floor (16 ops/layer, negligible). Gather inputs contiguous -> 2x b128.

#define PI_F 3.14159265358979323846f
#define NR 16

__device__ __forceinline__ float2 cmul(float2 a, float2 b) {
    return make_float2(a.x*b.x - a.y*b.y, a.x*b.y + a.y*b.x);
}
__device__ __forceinline__ float2 cmulc(float2 a, float2 b) {  // a * conj(b)
    return make_float2(a.x*b.x + a.y*b.y, a.y*b.x - a.x*b.y);
}

template<int RB>
__device__ __forceinline__ void ypow_reg(float2 (&a)[NR], float c, float s) {
    #pragma unroll
    for (int r0 = 0; r0 < NR; ++r0) {
        if ((r0 >> RB) & 1) continue;
        const int r1 = r0 | (1 << RB);
        float2 a0 = a[r0], a1 = a[r1];
        a[r0] = make_float2(c*a0.x - s*a1.x, c*a0.y - s*a1.y);
        a[r1] = make_float2(s*a0.x + c*a1.x, s*a0.y + c*a1.y);
    }
}

__device__ __forceinline__ void ypowA(float2 (&a)[NR], const float* __restrict__ th) {
    // layout A reg bit 3..0 = b9..b6 = q2..q5
    { float s,c; __sincosf(0.5f*PI_F*th[4],  &s,&c); ypow_reg<3>(a,c,s); }   // q2
    { float s,c; __sincosf(0.5f*PI_F*th[6],  &s,&c); ypow_reg<2>(a,c,s); }   // q3
    { float s,c; __sincosf(0.5f*PI_F*th[8],  &s,&c); ypow_reg<1>(a,c,s); }   // q4
    { float s,c; __sincosf(0.5f*PI_F*th[10], &s,&c); ypow_reg<0>(a,c,s); }   // q5
}
__device__ __forceinline__ void ypowB(float2 (&a)[NR], const float* __restrict__ th) {
    // layout B reg bit 3..0 = b3..b0 = q8..q11
    { float s,c; __sincosf(0.5f*PI_F*th[16], &s,&c); ypow_reg<3>(a,c,s); }   // q8
    { float s,c; __sincosf(0.5f*PI_F*th[18], &s,&c); ypow_reg<2>(a,c,s); }   // q9
    { float s,c; __sincosf(0.5f*PI_F*th[20], &s,&c); ypow_reg<1>(a,c,s); }   // q10
    { float s,c; __sincosf(0.5f*PI_F*th[22], &s,&c); ypow_reg<0>(a,c,s); }   // q11
}

// A->B transpose fusing Y_q6 (b5) and Y_q7 (b4). Wave-local (b11b10 untouched):
// wave w uses region [w*8192, w*8192+8192). Region slot = (x[9:6]<<4 | x[3:0])*4
// + x[5:4], so the 4 (b5,b4) gather inputs are a contiguous 32B run.
template<bool PRE_SYNC>
__device__ __forceinline__ void exchange_AB(float2 (&a)[NR], char* bufc,
                                            int w, int lane,
                                            float c6, float s6, float c7, float s7) {
    if (PRE_SYNC) __syncthreads();   // other waves' BA reads still cover this region
    const int wbyte = (w << 13) | ((lane & 15) << 5) | ((lane >> 4) << 3);
    #pragma unroll
    for (int r = 0; r < NR; ++r)     // amp x = w<<10 | r<<6 | lane
        *(float2*)(bufc + ((wbyte | (r << 9)) ^ ((r & 7) << 4))) = a[r];
    // wave-local write->read ordering: lockstep issue + lgkmcnt drain
    asm volatile("s_waitcnt lgkmcnt(0)" ::: "memory");
    const int g = lane >> 2;                        // output y[9:6]
    const float y60 = (lane & 2) ? s6 : c6;         // Y6[b5',0]  (b5' = L1)
    const float y61 = (lane & 2) ? c6 : -s6;        // Y6[b5',1]
    const float y70 = (lane & 1) ? s7 : c7;         // Y7[b4',0]  (b4' = L0)
    const float y71 = (lane & 1) ? c7 : -s7;        // Y7[b4',1]
    const float k00 = y60*y70, k01 = y60*y71, k10 = y61*y70, k11 = y61*y71;
    const int rbyte = (w << 13) | (g << 9);
    const int kx = (g & 7) << 4;                    // swizzle key, const per thread
    #pragma unroll
    for (int R = 0; R < NR; ++R) {                  // out y = w<<10 | L<<4 | R
        const int base = rbyte | (R << 5);
        float4 p01 = *(const float4*)(bufc + (base ^ kx));         // (b5b4)=00,01
        float4 p23 = *(const float4*)(bufc + ((base | 16) ^ kx));  // (b5b4)=10,11
        a[R] = make_float2(k00*p01.x + k01*p01.z + k10*p23.x + k11*p23.z,
                           k00*p01.y + k01*p01.w + k10*p23.y + k11*p23.w);
        // pressure fence: cap in-flight LDS loads at 8 x b128 (32 VGPRs)
        if ((R & 3) == 3) asm volatile("" ::: "memory");
    }
}

// B->A transpose fusing the CNOT-chain permutation (input x = y ^ (y>>1)) and
// the NEXT layer's Y_q0 (b11), Y_q1 (b10). Cross-wave. Store amp x at
// slot = T*4 + u*2 + v with v = x11, u = x10^x11, T = ((x9^u)<<9) | x[8:0];
// then the 4 (b11',b10') gather inputs for output y sit at slots t*4..t*4+3,
// t = y[9:0] ^ (y[9:0]>>1).
__device__ __forceinline__ void exchange_BA(float2 (&a)[NR], char* bufc,
                                            int w, int lane,
                                            float c0, float s0, float c1, float s1) {
    __syncthreads();                 // all waves done with their AB-region reads
    const int v_  = (w >> 1) & 1;
    const int u_  = v_ ^ (w & 1);
    const int l5u = (lane >> 5) ^ u_;
    const int wbyte = (l5u << 14) | ((lane & 31) << 9) | (u_ << 4) | (v_ << 3);
    const int wkx = (lane & 7) << 4;
    #pragma unroll
    for (int R = 0; R < NR; ++R)     // amp x = w<<10 | lane<<4 | R (layout B)
        *(float2*)(bufc + ((wbyte | (R << 5)) ^ wkx)) = a[R];
    __syncthreads();
    const float ky00 = (w & 2) ? s0 : c0;     // Y0[y11,0]
    const float ky01 = (w & 2) ? c0 : -s0;    // Y0[y11,1]
    const float ky10 = (w & 1) ? s1 : c1;     // Y1[y10,0]
    const float ky11 = (w & 1) ? c1 : -s1;    // Y1[y10,1]
    const float k00 = ky10*ky00, k01 = ky10*ky01, k10 = ky11*ky00, k11 = ky11*ky01;
    #pragma unroll
    for (int r = 0; r < NR; ++r) {            // out y = w<<10 | r<<6 | lane (layout A)
        const int ylow = (r << 6) | lane;
        const int t = ylow ^ (ylow >> 1);     // 10-bit Gray inverse
        const int base = t << 5;
        const int kx = t & 0x70;              // ((base>>9)&7)<<4
        float4 p01 = *(const float4*)(bufc + (base ^ kx));         // (u,v)=00,01
        float4 p23 = *(const float4*)(bufc + ((base | 16) ^ kx));  // (u,v)=10,11
        a[r] = make_float2(k00*p01.x + k01*p01.z + k10*p23.x + k11*p23.z,
                           k00*p01.y + k01*p01.w + k10*p23.y + k11*p23.w);
        // pressure fence: cap in-flight LDS loads at 8 x b128 (32 VGPRs)
        if ((r & 3) == 3) asm volatile("" ::: "memory");
    }
}

// Fused Z for all 12 qubits, state in layout B. Per-amp factor as a Gray-code
// running complex product (1 sincos for the wave+lane part, 4 for reg bits).
__device__ __forceinline__ void fused_z_B(float2 (&a)[NR], int w, int lane,
                                          const float* __restrict__ th) {
    float alpha = ((w & 2) ? th[1] : 0.0f) + ((w & 1) ? th[3] : 0.0f);  // q0,q1
    #pragma unroll
    for (int k = 0; k < 6; ++k)               // lane bit k <-> q(7-k)
        alpha += ((lane >> k) & 1) ? th[2*(7-k)+1] : 0.0f;
    float2 zb; __sincosf(PI_F * alpha, &zb.y, &zb.x);
    float2 zq[4];
    #pragma unroll
    for (int j = 0; j < 4; ++j)               // reg bit j <-> q(11-j)
        __sincosf(PI_F * th[2*(11-j)+1], &zq[j].y, &zq[j].x);
    float2 cur = zb;
    a[0] = cmul(a[0], cur);
    #pragma unroll
    for (int k = 1; k < NR; ++k) {
        const int bit = __builtin_ctz(k);
        const int g = k ^ (k >> 1);
        cur = ((g >> bit) & 1) ? cmul(cur, zq[bit]) : cmulc(cur, zq[bit]);
        a[g] = cmul(a[g], cur);
    }
}

__global__ __launch_bounds__(256) void vqc_kernel(
    const float* __restrict__ inputs,   // [1024,12]
    const float* __restrict__ thetas,   // [72] = [3][12][2]
    float* __restrict__ out)            // [1024,12]
{
    __shared__ __align__(16) char bufc[32768];   // swizzled exchange buffer
    __shared__ float redBuf[48];

    const int b = blockIdx.x;
    const int tid = threadIdx.x;
    const int w = tid >> 6;          // w1=b11(q0), w0=b10(q1)
    const int lane = tid & 63;
    const float* x = inputs + b * 12;

    float2 a[NR];

    // ---- Encoding (closed form) with layer-0 Y_q0 AND Y_q1 folded in.
    // amp = 2^-6 * F0(b11) * F1(b10) * cis(pi * sum_{q>=2 set} x_q)
    float phb = 0.0f;
    #pragma unroll
    for (int k = 0; k < 6; ++k)               // layout A lane bit k <-> q(11-k)
        phb += ((lane >> k) & 1) ? x[11 - k] : 0.0f;
    float2 cisb; __sincosf(PI_F * phb, &cisb.y, &cisb.x);
    float2 E0; __sincosf(PI_F * x[0], &E0.y, &E0.x);
    float2 E1; __sincosf(PI_F * x[1], &E1.y, &E1.x);
    float sa, ca; __sincosf(0.5f * PI_F * thetas[0], &sa, &ca);
    float sb, cb; __sincosf(0.5f * PI_F * thetas[2], &sb, &cb);
    float2 F0 = (w & 2) ? make_float2(sa + ca*E0.x,  ca*E0.y)
                        : make_float2(ca - sa*E0.x, -sa*E0.y);
    float2 F1 = (w & 1) ? make_float2(sb + cb*E1.x,  cb*E1.y)
                        : make_float2(cb - sb*E1.x, -sb*E1.y);
    float2 g0 = cmul(cmul(F0, F1), cisb);
    g0.x *= 0.015625f; g0.y *= 0.015625f;
    float2 zr[4];
    #pragma unroll
    for (int j = 0; j < 4; ++j)               // layout A reg bit j <-> q(5-j)
        __sincosf(PI_F * x[5 - j], &zr[j].y, &zr[j].x);
    {
        float2 cur = g0;
        a[0] = cur;
        #pragma unroll
        for (int k = 1; k < NR; ++k) {
            const int bit = __builtin_ctz(k);
            const int g = k ^ (k >> 1);
            cur = ((g >> bit) & 1) ? cmul(cur, zr[bit]) : cmulc(cur, zr[bit]);
            a[g] = cur;
        }
    }

    const float* th0 = thetas;
    const float* th1 = thetas + 24;
    const float* th2 = thetas + 48;

    // ----- layer 0 -----
    ypowA(a, th0);
    { float s6,c6,s7,c7;
      __sincosf(0.5f*PI_F*th0[12], &s6,&c6);
      __sincosf(0.5f*PI_F*th0[14], &s7,&c7);
      exchange_AB<false>(a, bufc, w, lane, c6,s6,c7,s7); }
    ypowB(a, th0);
    fused_z_B(a, w, lane, th0);
    { float s0,c0,s1,c1;
      __sincosf(0.5f*PI_F*th1[0], &s0,&c0);
      __sincosf(0.5f*PI_F*th1[2], &s1,&c1);
      exchange_BA(a, bufc, w, lane, c0,s0,c1,s1); }

    // ----- layer 1 -----
    ypowA(a, th1);
    { float s6,c6,s7,c7;
      __sincosf(0.5f*PI_F*th1[12], &s6,&c6);
      __sincosf(0.5f*PI_F*th1[14], &s7,&c7);
      exchange_AB<true>(a, bufc, w, lane, c6,s6,c7,s7); }
    ypowB(a, th1);
    fused_z_B(a, w, lane, th1);
    { float s0,c0,s1,c1;
      __sincosf(0.5f*PI_F*th2[0], &s0,&c0);
      __sincosf(0.5f*PI_F*th2[2], &s1,&c1);
      exchange_BA(a, bufc, w, lane, c0,s0,c1,s1); }

    // ----- layer 2 (no CNOT; Zs dropped — diagonal before |amp|^2) -----
    ypowA(a, th2);
    { float s6,c6,s7,c7;
      __sincosf(0.5f*PI_F*th2[12], &s6,&c6);
      __sincosf(0.5f*PI_F*th2[14], &s7,&c7);
      exchange_AB<true>(a, bufc, w, lane, c6,s6,c7,s7); }
    ypowB(a, th2);

    // ---- Readout in layout B: q0=w1, q1=w0, q2..q7=lane bits 5..0, q8..q11=reg
    float totalP = 0.0f;
    float D[4] = {0, 0, 0, 0};
    #pragma unroll
    for (int r = 0; r < NR; ++r) {
        const float p = a[r].x * a[r].x + a[r].y * a[r].y;
        totalP += p;
        #pragma unroll
        for (int j = 0; j < 4; ++j)
            D[j] += ((r >> j) & 1) ? -p : p;
    }
    #pragma unroll
    for (int q = 0; q < 12; ++q) {
        float v;
        if (q == 0)      v = (w & 2) ? -totalP : totalP;
        else if (q == 1) v = (w & 1) ? -totalP : totalP;
        else if (q <= 7) v = ((lane >> (7 - q)) & 1) ? -totalP : totalP;
        else             v = D[11 - q];
        #pragma unroll
        for (int off = 32; off >= 1; off >>= 1)
            v += __shfl_xor(v, off, 64);
        if (lane == 0) redBuf[w * 12 + q] = v;
    }
    __syncthreads();
    if (tid < 12)
        out[b * 12 + tid] = redBuf[tid] + redBuf[12 + tid]
                          + redBuf[24 + tid] + redBuf[36 + tid];
}

extern "C" void kernel_launch(void* const* d_in, const int* in_sizes, int n_in,
                              void* d_out, int out_size, void* d_ws, size_t ws_size,
                              hipStream_t stream) {
    const float* inputs = (const float*)d_in[0];   // [1024,12] f32
    const float* thetas = (const float*)d_in[1];   // [72] f32
    float* out = (float*)d_out;                    // [1024,12] f32
    vqc_kernel<<<dim3(1024), dim3(256), 0, stream>>>(inputs, thetas, out);
}